// Round 10
// baseline (293.951 us; speedup 1.0000x reference)
//
#include <hip/hip_runtime.h>

#define N_   2
#define C_   256
#define H_   55
#define W_   128
#define HW_  (H_ * W_)      // 7040
#define NPIX (N_ * HW_)     // 14080
#define PB   16             // pixels per block (one h-row segment)
#define NBLK (NPIX / PB)    // 880 = 8 * 110
#define BPX  (NBLK / 8)     // 110 blocks per XCD band
#define F1LD 260            // f1 LDS leading dim
#define MAXR 12             // max staged rows
#define NCOL 32             // staged cols (fixed)
#define SLOTS (MAXR * NCOL) // 384
#define SLD  36             // padded floats per slot (32ch chunk + 4 pad)

#define OFF_CV  0
#define OFF_VAL (NPIX * 25)          // 352000
#define OFF_XY  (OFF_VAL + NPIX)     // 366080

typedef float f32x4 __attribute__((ext_vector_type(4)));

// ---------------------------------------------------------------------------
// Transpose f2 only: [C, HW] -> [HW, C] per n.  blockIdx.z = n.
// ---------------------------------------------------------------------------
__global__ __launch_bounds__(256) void transpose_f2(const float* __restrict__ f2,
                                                    float* __restrict__ f2t) {
    __shared__ float tile[64][65];
    const int n = blockIdx.z;
    const float* __restrict__ src = f2 + (size_t)n * C_ * HW_;
    float* __restrict__ dst = f2t + (size_t)n * HW_ * C_;

    const int p0 = blockIdx.x * 64;
    const int c0 = blockIdx.y * 64;
    const int q = threadIdx.x & 15;
    const int r = threadIdx.x >> 4;

    #pragma unroll
    for (int rr = r; rr < 64; rr += 16) {
        const f32x4 v = __builtin_nontemporal_load(
            (const f32x4*)(src + (size_t)(c0 + rr) * HW_ + p0 + q * 4));
        tile[rr][q * 4 + 0] = v.x;
        tile[rr][q * 4 + 1] = v.y;
        tile[rr][q * 4 + 2] = v.z;
        tile[rr][q * 4 + 3] = v.w;
    }
    __syncthreads();

    #pragma unroll
    for (int j = 0; j < 4; ++j) {
        const int pr = r + 16 * j;
        float4 v;
        v.x = tile[q * 4 + 0][pr];
        v.y = tile[q * 4 + 1][pr];
        v.z = tile[q * 4 + 2][pr];
        v.w = tile[q * 4 + 3][pr];
        *(float4*)(dst + (size_t)(p0 + pr) * C_ + c0 + q * 4) = v;
    }
}

__device__ __forceinline__ float dot4(const float4 a, const float4 b) {
    return a.x * b.x + a.y * b.y + a.z * b.z + a.w * b.w;
}

// VALU-only 16-lane sum (DPP butterfly within a DPP row of 16 lanes).
__device__ __forceinline__ float dpp_add16(float x) {
    int v;
    v = __builtin_amdgcn_update_dpp(0, __float_as_int(x), 0xB1, 0xF, 0xF, true);  // xor1
    x += __int_as_float(v);
    v = __builtin_amdgcn_update_dpp(0, __float_as_int(x), 0x4E, 0xF, 0xF, true);  // xor2
    x += __int_as_float(v);
    v = __builtin_amdgcn_update_dpp(0, __float_as_int(x), 0x141, 0xF, 0xF, true); // half_mirror
    x += __int_as_float(v);
    v = __builtin_amdgcn_update_dpp(0, __float_as_int(x), 0x140, 0xF, 0xF, true); // mirror
    x += __int_as_float(v);
    return x;
}

// VALU-only 8-lane sum: xor1, xor2, then xor7 (row_half_mirror) completes the
// butterfly over each 8-lane group ({1,2,7} generates Z2^3 sums).
__device__ __forceinline__ float dpp_add8(float x) {
    int v;
    v = __builtin_amdgcn_update_dpp(0, __float_as_int(x), 0xB1, 0xF, 0xF, true);  // xor1
    x += __int_as_float(v);
    v = __builtin_amdgcn_update_dpp(0, __float_as_int(x), 0x4E, 0xF, 0xF, true);  // xor2
    x += __int_as_float(v);
    v = __builtin_amdgcn_update_dpp(0, __float_as_int(x), 0x141, 0xF, 0xF, true); // xor7 in 8-group
    x += __int_as_float(v);
    return x;
}

// Blend 36 D values -> 25 cv, store cv, then WTA (first-occurrence argmax).
__device__ __forceinline__ void blend_wta(const float* __restrict__ Drow,
                                          float wx, float wy, int pix, int lane,
                                          float* __restrict__ out) {
    float cv = 0.f;
    if (lane < 25) {
        const int i = lane / 5, j = lane - i * 5;   // i -> dy, j -> dx
        const float D00 = Drow[i * 6 + j];
        const float D01 = Drow[i * 6 + j + 1];
        const float D10 = Drow[i * 6 + j + 6];
        const float D11 = Drow[i * 6 + j + 7];
        cv = (1.f - wx) * (1.f - wy) * D00 + wx * (1.f - wy) * D01
           + (1.f - wx) * wy * D10 + wx * wy * D11;
        __builtin_nontemporal_store(cv, out + OFF_CV + (size_t)pix * 25 + lane);
    }
    float v  = (lane < 25) ? cv : -3.4e38f;
    int  idx = (lane < 25) ? lane : 25;
    #pragma unroll
    for (int off = 16; off >= 1; off >>= 1) {
        const float v2 = __shfl_down(v, off, 32);
        const int   i2 = __shfl_down(idx, off, 32);
        if (v2 > v || (v2 == v && i2 < idx)) { v = v2; idx = i2; }
    }
    if (lane == 0) {
        __builtin_nontemporal_store(v, out + OFF_VAL + pix);
        __builtin_nontemporal_store((float)(idx % 5), out + OFF_XY + pix);
        __builtin_nontemporal_store((float)(idx / 5), out + OFF_XY + NPIX + pix);
    }
}

// ---------------------------------------------------------------------------
// Main kernel: 16 px/block, 512 threads = 8 waves x 2 px.
// Fast path: per-block bbox of all 16 gather windows staged f2t->LDS in 8
// channel-chunks of 32; all 36 dots served from LDS. Rare outlier blocks
// (bbox > 12x32) take the exact global-gather fallback.
// ---------------------------------------------------------------------------
__global__ __launch_bounds__(512, 4) void costvol_kernel(const float* __restrict__ flow,
                                                         const float* __restrict__ f1,
                                                         const float* __restrict__ f2t,
                                                         float* __restrict__ out) {
    __shared__ __align__(16) float f1sh[PB][F1LD];     // 16.6 KB
    __shared__ __align__(16) float stage[SLOTS * SLD]; // 55.3 KB
    __shared__ float Dsh[8][36];
    __shared__ float wxs[PB], wys[PB];
    __shared__ int   ix0s[PB], iy0s[PB];

    const int tid  = threadIdx.x;
    const int b    = blockIdx.x;
    const int xcd  = b & 7;
    const int kk   = b >> 3;
    const int pix0 = (xcd * BPX + kk) * PB;   // XCD-banded, bijective
    const int n     = pix0 / HW_;
    const int prem0 = pix0 - n * HW_;
    const int h     = prem0 >> 7;
    const int w0    = prem0 & (W_ - 1);

    const float* __restrict__ flown = flow + (size_t)n * 2 * HW_;
    if (tid < PB) {
        const float fx = flown[h * W_ + w0 + tid];
        const float fy = flown[HW_ + h * W_ + w0 + tid];
        const float cx = (float)(w0 + tid) + fx;
        const float cy = (float)h + fy;
        const float x0f = floorf(cx), y0f = floorf(cy);
        wxs[tid] = cx - x0f;  wys[tid] = cy - y0f;
        ix0s[tid] = (int)x0f; iy0s[tid] = (int)y0f;
    }

    // Stage f1[*, pix0..pix0+15] coalesced (float4 over 4 consecutive pixels).
    {
        const int px4   = tid & 3;
        const int cbase = tid >> 2;          // 0..127
        #pragma unroll
        for (int it = 0; it < 2; ++it) {
            const int c = cbase + it * 128;
            const f32x4 v = __builtin_nontemporal_load(
                (const f32x4*)(f1 + ((size_t)n * C_ + c) * HW_ + prem0 + px4 * 4));
            f1sh[px4 * 4 + 0][c] = v.x;
            f1sh[px4 * 4 + 1][c] = v.y;
            f1sh[px4 * 4 + 2][c] = v.z;
            f1sh[px4 * 4 + 3][c] = v.w;
        }
    }
    __syncthreads();

    // Block bbox (all threads compute identically from LDS).
    int mnIx = ix0s[0], mxIx = ix0s[0], mnIy = iy0s[0], mxIy = iy0s[0];
    #pragma unroll
    for (int t = 1; t < PB; ++t) {
        mnIx = min(mnIx, ix0s[t]); mxIx = max(mxIx, ix0s[t]);
        mnIy = min(mnIy, iy0s[t]); mxIy = max(mxIy, iy0s[t]);
    }
    const int Ra  = max(mnIy - 2, 0);
    const int Rb  = min(mxIy + 3, H_ - 1);
    const int NRc = Rb - Ra + 1;
    const int Xb  = min(max(mnIx - 2, 0) & ~3, W_ - NCOL);   // in [0, 96], 16B-aligned
    const bool fb = (NRc < 1) || (NRc > MAXR) ||
                    ((min(mxIx + 3, W_ - 1) - Xb) > NCOL - 1);
    const int fbu = __builtin_amdgcn_readfirstlane((int)fb); // block-uniform scalar

    const int wv   = tid >> 6;
    const int lane = tid & 63;
    const float4* __restrict__ f2t4 = (const float4*)f2t + (size_t)n * HW_ * (C_ / 4);

    if (!fbu) {
        // ---------------- staged fast path ----------------
        const int oct = lane >> 3;   // 0..7 sample slot within pass
        const int cg  = lane & 7;    // 0..7 channel quad within 32-ch chunk
        float4* __restrict__ st4 = (float4*)stage;
        const float4* __restrict__ f1sh4 = (const float4*)&f1sh[0][0];
        const int plA = wv * 2, plB = wv * 2 + 1;
        const int ix0A = ix0s[plA], iy0A = iy0s[plA];
        const int ix0B = ix0s[plB], iy0B = iy0s[plB];

        // Per-(pixel,pass) slot + validity, all named registers (no arrays).
#define SPRE(S, P)                                                              \
        int slot##S##P; float msk##S##P; float D##S##P = 0.f;                   \
        { const int s  = (P) * 8 + oct;                                         \
          const int dy = s / 6;                                                 \
          const int sy = iy0##S - 2 + dy, sx = ix0##S - 2 + (s - 6 * dy);       \
          const bool vv = (s < 36) && ((unsigned)sy < (unsigned)H_) &&          \
                          ((unsigned)sx < (unsigned)W_);                        \
          slot##S##P = vv ? ((sy - Ra) * NCOL + (sx - Xb)) : 0;                 \
          msk##S##P  = vv ? 1.f : 0.f; }
        SPRE(A,0) SPRE(A,1) SPRE(A,2) SPRE(A,3) SPRE(A,4)
        SPRE(B,0) SPRE(B,1) SPRE(B,2) SPRE(B,3) SPRE(B,4)
#undef SPRE

        const int nf4 = NRc * 256;   // float4s to stage per chunk
        for (int k = 0; k < 8; ++k) {
            // stage chunk k (channels 32k..32k+32) for the whole bbox
            for (int j = tid; j < nf4; j += 512) {
                const int q = j & 7, slot = j >> 3;
                const int col = slot & (NCOL - 1), rr = slot >> 5;
                st4[slot * (SLD / 4) + q] =
                    f2t4[(size_t)((Ra + rr) * W_ + Xb + col) * (C_ / 4) + k * 8 + q];
            }
            __syncthreads();
            const float4 aA = f1sh4[plA * (F1LD / 4) + k * 8 + cg];
            const float4 aB = f1sh4[plB * (F1LD / 4) + k * 8 + cg];
#define SACC(S, P) { const float4 vq = st4[slot##S##P * (SLD / 4) + cg];        \
                     D##S##P += msk##S##P * dot4(a##S, vq); }
            SACC(A,0) SACC(A,1) SACC(A,2) SACC(A,3) SACC(A,4)
            SACC(B,0) SACC(B,1) SACC(B,2) SACC(B,3) SACC(B,4)
#undef SACC
            __syncthreads();
        }

#define SRED(S, P) { const float t = dpp_add8(D##S##P);                         \
                     const int s = (P) * 8 + oct;                               \
                     if (cg == 0 && s < 36) Dsh[wv][s] = t; }
        SRED(A,0) SRED(A,1) SRED(A,2) SRED(A,3) SRED(A,4)
        __builtin_amdgcn_wave_barrier();
        blend_wta(Dsh[wv], wxs[plA], wys[plA], pix0 + plA, lane, out);
        __builtin_amdgcn_wave_barrier();
        SRED(B,0) SRED(B,1) SRED(B,2) SRED(B,3) SRED(B,4)
        __builtin_amdgcn_wave_barrier();
        blend_wta(Dsh[wv], wxs[plB], wys[plB], pix0 + plB, lane, out);
#undef SRED
    } else {
        // ---------------- exact fallback (rare outlier blocks) ----------------
        const int sgrp = lane >> 4;   // 0..3 sample slot
        const int cgrp = lane & 15;   // 0..15 channel chunk
        for (int pp = 0; pp < 2; ++pp) {
            const int pl  = wv * 2 + pp;
            const int ix0 = ix0s[pl], iy0 = iy0s[pl];
            const float* fr = &f1sh[pl][cgrp * 4];
            const float4 a0 = *(const float4*)(fr);
            const float4 a1 = *(const float4*)(fr + 64);
            const float4 a2 = *(const float4*)(fr + 128);
            const float4 a3 = *(const float4*)(fr + 192);
            #pragma unroll
            for (int p = 0; p < 9; ++p) {
                const int s  = p * 4 + sgrp;
                const int ly = s / 6, lx = s - 6 * ly;
                const int sy = iy0 - 2 + ly, sx = ix0 - 2 + lx;
                float part = 0.f;
                if (((unsigned)sy < (unsigned)H_) && ((unsigned)sx < (unsigned)W_)) {
                    const float4* __restrict__ bp =
                        f2t4 + (size_t)(sy * W_ + sx) * (C_ / 4) + cgrp;
                    part = dot4(a0, bp[0]) + dot4(a1, bp[16])
                         + dot4(a2, bp[32]) + dot4(a3, bp[48]);
                }
                part = dpp_add16(part);
                if (cgrp == 0) Dsh[wv][s] = part;
            }
            __builtin_amdgcn_wave_barrier();
            blend_wta(Dsh[wv], wxs[pl], wys[pl], pix0 + pl, lane, out);
            __builtin_amdgcn_wave_barrier();
        }
    }
}

// ---------------------------------------------------------------------------
extern "C" void kernel_launch(void* const* d_in, const int* in_sizes, int n_in,
                              void* d_out, int out_size, void* d_ws, size_t ws_size,
                              hipStream_t stream) {
    const float* flow = (const float*)d_in[0];
    const float* f1   = (const float*)d_in[1];
    const float* f2   = (const float*)d_in[2];
    float* out = (float*)d_out;

    float* f2t = (float*)d_ws;                       // [N, HW, C]

    transpose_f2<<<dim3(HW_ / 64, C_ / 64, N_), 256, 0, stream>>>(f2, f2t);
    costvol_kernel<<<dim3(NBLK), 512, 0, stream>>>(flow, f1, f2t, out);
}

// Round 11
// 113.215 us; speedup vs baseline: 2.5964x; 2.5964x over previous
//
#include <hip/hip_runtime.h>

#define N_   2
#define C_   256
#define H_   55
#define W_   128
#define HW_  (H_ * W_)      // 7040
#define NPIX (N_ * HW_)     // 14080
#define PB   4              // pixels per block (1 per wave)
#define NBLK (NPIX / PB)    // 3520 = 8 * 440
#define BPX  (NBLK / 8)     // 440 blocks per XCD band

#define OFF_CV  0
#define OFF_VAL (NPIX * 25)          // 352000
#define OFF_XY  (OFF_VAL + NPIX)     // 366080

typedef float f32x4 __attribute__((ext_vector_type(4)));

// ---------------------------------------------------------------------------
// Transpose f2 only: [C, HW] -> [HW, C] per n.  blockIdx.z = n.
// ---------------------------------------------------------------------------
__global__ __launch_bounds__(256) void transpose_f2(const float* __restrict__ f2,
                                                    float* __restrict__ f2t) {
    __shared__ float tile[64][65];
    const int n = blockIdx.z;
    const float* __restrict__ src = f2 + (size_t)n * C_ * HW_;
    float* __restrict__ dst = f2t + (size_t)n * HW_ * C_;

    const int p0 = blockIdx.x * 64;
    const int c0 = blockIdx.y * 64;
    const int q = threadIdx.x & 15;
    const int r = threadIdx.x >> 4;

    #pragma unroll
    for (int rr = r; rr < 64; rr += 16) {
        const f32x4 v = __builtin_nontemporal_load(
            (const f32x4*)(src + (size_t)(c0 + rr) * HW_ + p0 + q * 4));
        tile[rr][q * 4 + 0] = v.x;
        tile[rr][q * 4 + 1] = v.y;
        tile[rr][q * 4 + 2] = v.z;
        tile[rr][q * 4 + 3] = v.w;
    }
    __syncthreads();

    #pragma unroll
    for (int j = 0; j < 4; ++j) {
        const int pr = r + 16 * j;
        float4 v;
        v.x = tile[q * 4 + 0][pr];
        v.y = tile[q * 4 + 1][pr];
        v.z = tile[q * 4 + 2][pr];
        v.w = tile[q * 4 + 3][pr];
        *(float4*)(dst + (size_t)(p0 + pr) * C_ + c0 + q * 4) = v;
    }
}

__device__ __forceinline__ float dot4(const float4 a, const float4 b) {
    return a.x * b.x + a.y * b.y + a.z * b.z + a.w * b.w;
}

// VALU-only 16-lane sum (DPP butterfly within a DPP row of 16 lanes).
__device__ __forceinline__ float dpp_add16(float x) {
    int v;
    v = __builtin_amdgcn_update_dpp(0, __float_as_int(x), 0xB1, 0xF, 0xF, true);  // xor1
    x += __int_as_float(v);
    v = __builtin_amdgcn_update_dpp(0, __float_as_int(x), 0x4E, 0xF, 0xF, true);  // xor2
    x += __int_as_float(v);
    v = __builtin_amdgcn_update_dpp(0, __float_as_int(x), 0x141, 0xF, 0xF, true); // half_mirror
    x += __int_as_float(v);
    v = __builtin_amdgcn_update_dpp(0, __float_as_int(x), 0x140, 0xF, 0xF, true); // mirror
    x += __int_as_float(v);
    return x;
}

// Blend 36 D values -> 25 cv, store cv, then WTA (first-occurrence argmax).
__device__ __forceinline__ void blend_wta(const float* __restrict__ Drow,
                                          float wx, float wy, int pix, int lane,
                                          float* __restrict__ out) {
    float cv = 0.f;
    if (lane < 25) {
        const int i = lane / 5, j = lane - i * 5;   // i -> dy, j -> dx
        const float D00 = Drow[i * 6 + j];
        const float D01 = Drow[i * 6 + j + 1];
        const float D10 = Drow[i * 6 + j + 6];
        const float D11 = Drow[i * 6 + j + 7];
        cv = (1.f - wx) * (1.f - wy) * D00 + wx * (1.f - wy) * D01
           + (1.f - wx) * wy * D10 + wx * wy * D11;
        __builtin_nontemporal_store(cv, out + OFF_CV + (size_t)pix * 25 + lane);
    }
    float v  = (lane < 25) ? cv : -3.4e38f;
    int  idx = (lane < 25) ? lane : 25;
    #pragma unroll
    for (int off = 16; off >= 1; off >>= 1) {
        const float v2 = __shfl_down(v, off, 32);
        const int   i2 = __shfl_down(idx, off, 32);
        if (v2 > v || (v2 == v && i2 < idx)) { v = v2; idx = i2; }
    }
    if (lane == 0) {
        __builtin_nontemporal_store(v, out + OFF_VAL + pix);
        __builtin_nontemporal_store((float)(idx % 5), out + OFF_XY + pix);
        __builtin_nontemporal_store((float)(idx / 5), out + OFF_XY + NPIX + pix);
    }
}

// ---------------------------------------------------------------------------
// Main kernel: 4 px/block (1 px per wave), 256 threads.
// Per pass (4 samples): stage next pass's 4 sample rows (4 x 1KB) direct to
// LDS via global_load_lds_dwordx4 (no data VGPRs -> deep in-flight queue),
// counted s_waitcnt vmcnt(4) between passes (T4; never drain mid-loop).
// Compute path = verified rounds-5..9 math (same mapping/order/results).
// ---------------------------------------------------------------------------
__global__ __launch_bounds__(256) void costvol_kernel(const float* __restrict__ flow,
                                                      const float* __restrict__ f1,
                                                      const float* __restrict__ f2t,
                                                      float* __restrict__ out) {
    __shared__ float f1sh[PB][C_];                          // 4 KB
    __shared__ __align__(16) float stage[4][2][4][C_];      // 32 KB: [wave][buf][slot][ch]
    __shared__ float Dsh[4][36];
    __shared__ float wxs[PB], wys[PB];
    __shared__ int   ix0s[PB], iy0s[PB];

    const int tid  = threadIdx.x;
    const int b    = blockIdx.x;
    const int xcd  = b & 7;
    const int kk   = b >> 3;
    const int pix0 = (xcd * BPX + kk) * PB;   // XCD-banded, bijective; no n/row straddle
    const int n     = pix0 / HW_;
    const int prem0 = pix0 - n * HW_;
    const int h     = prem0 >> 7;
    const int w0    = prem0 & (W_ - 1);

    const float* __restrict__ flown = flow + (size_t)n * 2 * HW_;
    if (tid < PB) {
        const float fx = flown[h * W_ + w0 + tid];
        const float fy = flown[HW_ + h * W_ + w0 + tid];
        const float cx = (float)(w0 + tid) + fx;
        const float cy = (float)h + fy;
        const float x0f = floorf(cx), y0f = floorf(cy);
        wxs[tid] = cx - x0f;  wys[tid] = cy - y0f;
        ix0s[tid] = (int)x0f; iy0s[tid] = (int)y0f;
    }

    // f1 stage: thread t = channel t, float4 spans the block's 4 pixels.
    {
        const f32x4 v = __builtin_nontemporal_load(
            (const f32x4*)(f1 + ((size_t)n * C_ + tid) * HW_ + prem0));
        f1sh[0][tid] = v.x;
        f1sh[1][tid] = v.y;
        f1sh[2][tid] = v.z;
        f1sh[3][tid] = v.w;
    }
    __syncthreads();   // params + f1sh visible; vmcnt drained here

    const int wv   = tid >> 6;
    const int lane = tid & 63;
    const int sgrp = lane >> 4;     // 0..3 sample slot within pass
    const int cgrp = lane & 15;     // 0..15 channel chunk

    const int   ix0 = ix0s[wv], iy0 = iy0s[wv];
    const float wx  = wxs[wv],  wy  = wys[wv];

    // Per-pass window offsets for THIS lane's sample (s = 4p + sgrp), named.
    const int s0 = sgrp,      s1 = 4 + sgrp,  s2 = 8 + sgrp,  s3 = 12 + sgrp;
    const int s4 = 16 + sgrp, s5 = 20 + sgrp, s6 = 24 + sgrp, s7 = 28 + sgrp;
    const int s8 = 32 + sgrp;
    const int ly0 = s0 / 6, lx0 = s0 - 6 * ly0;
    const int ly1 = s1 / 6, lx1 = s1 - 6 * ly1;
    const int ly2 = s2 / 6, lx2 = s2 - 6 * ly2;
    const int ly3 = s3 / 6, lx3 = s3 - 6 * ly3;
    const int ly4 = s4 / 6, lx4 = s4 - 6 * ly4;
    const int ly5 = s5 / 6, lx5 = s5 - 6 * ly5;
    const int ly6 = s6 / 6, lx6 = s6 - 6 * ly6;
    const int ly7 = s7 / 6, lx7 = s7 - 6 * ly7;
    const int ly8 = s8 / 6, lx8 = s8 - 6 * ly8;

    const float* __restrict__ f2n = f2t + (size_t)n * HW_ * C_;
    const float* fr = &f1sh[wv][cgrp * 4];
    const float4 a0 = *(const float4*)(fr);
    const float4 a1 = *(const float4*)(fr + 64);
    const float4 a2 = *(const float4*)(fr + 128);
    const float4 a3 = *(const float4*)(fr + 192);

// Issue one sample row (1KB) direct to LDS: 64 lanes x 16B contiguous.
#define ISS1(P, Q, BUF) {                                                        \
        constexpr int s_  = 4 * (P) + (Q);                                       \
        constexpr int dy_ = s_ / 6;                                              \
        constexpr int dx_ = s_ - 6 * dy_;                                        \
        const int scy = min(max(iy0 - 2 + dy_, 0), H_ - 1);                      \
        const int scx = min(max(ix0 - 2 + dx_, 0), W_ - 1);                      \
        const float* gsrc = f2n + ((size_t)(scy * W_ + scx) << 8) + (lane << 2); \
        __builtin_amdgcn_global_load_lds(                                        \
            (const __attribute__((address_space(1))) void*)gsrc,                 \
            (__attribute__((address_space(3))) void*)&stage[wv][BUF][Q][0],      \
            16, 0, 0); }
#define ISSUE(P, BUF) ISS1(P, 0, BUF) ISS1(P, 1, BUF) ISS1(P, 2, BUF) ISS1(P, 3, BUF)

// Counted wait: N loads may stay in flight (the just-issued next pass).
#define VMW(NN) { asm volatile("s_waitcnt vmcnt(" #NN ")" ::: "memory");         \
                  __builtin_amdgcn_sched_barrier(0); }

// Compute pass P from buffer BUF: lane reads its sample's 16-ch chunk.
#define COMPUTE(P, BUF) {                                                        \
        const int sy = iy0 - 2 + ly##P, sx = ix0 - 2 + lx##P;                    \
        const float msk = (((unsigned)sy < (unsigned)H_) &&                      \
                          ((unsigned)sx < (unsigned)W_)) ? 1.f : 0.f;            \
        const float4* bp = (const float4*)&stage[wv][BUF][sgrp][0] + cgrp;       \
        const float part = msk * (dot4(a0, bp[0])  + dot4(a1, bp[16])            \
                                + dot4(a2, bp[32]) + dot4(a3, bp[48]));          \
        const float t_ = dpp_add16(part);                                        \
        if (cgrp == 0) Dsh[wv][4 * (P) + sgrp] = t_; }

    ISSUE(0, 0)
    ISSUE(1, 1) VMW(4) COMPUTE(0, 0)
    ISSUE(2, 0) VMW(4) COMPUTE(1, 1)
    ISSUE(3, 1) VMW(4) COMPUTE(2, 0)
    ISSUE(4, 0) VMW(4) COMPUTE(3, 1)
    ISSUE(5, 1) VMW(4) COMPUTE(4, 0)
    ISSUE(6, 0) VMW(4) COMPUTE(5, 1)
    ISSUE(7, 1) VMW(4) COMPUTE(6, 0)
    ISSUE(8, 0) VMW(4) COMPUTE(7, 1)
    VMW(0)      COMPUTE(8, 0)

#undef ISS1
#undef ISSUE
#undef VMW
#undef COMPUTE

    __builtin_amdgcn_wave_barrier();   // Dsh writes before same-wave reads
    blend_wta(Dsh[wv], wx, wy, pix0 + wv, lane, out);
}

// ---------------------------------------------------------------------------
extern "C" void kernel_launch(void* const* d_in, const int* in_sizes, int n_in,
                              void* d_out, int out_size, void* d_ws, size_t ws_size,
                              hipStream_t stream) {
    const float* flow = (const float*)d_in[0];
    const float* f1   = (const float*)d_in[1];
    const float* f2   = (const float*)d_in[2];
    float* out = (float*)d_out;

    float* f2t = (float*)d_ws;                       // [N, HW, C]

    transpose_f2<<<dim3(HW_ / 64, C_ / 64, N_), 256, 0, stream>>>(f2, f2t);
    costvol_kernel<<<dim3(NBLK), 256, 0, stream>>>(flow, f1, f2t, out);
}